// Round 1
// baseline (2845.409 us; speedup 1.0000x reference)
//
#include <hip/hip_runtime.h>
#include <hip/hip_bf16.h>

#define N_NODES 100000
#define N_EDGES 1600000
#define F 128

// ---------------- CSR build ----------------

__global__ void count_deg_kernel(const int* __restrict__ dst, int* __restrict__ deg, int n) {
    int i = blockIdx.x * 256 + threadIdx.x;
    if (i < n) atomicAdd(&deg[dst[i]], 1);
}

// single block, 1024 threads: exclusive scan of deg -> row_ptr, cursor; also inv_deg
__global__ void scan_kernel(const int* __restrict__ deg, int* __restrict__ row_ptr,
                            int* __restrict__ cursor, float* __restrict__ inv_deg) {
    __shared__ int wsum[16];
    __shared__ int s_chunk;
    __shared__ int s_running;
    int t = threadIdx.x;
    int lane = t & 63, wid = t >> 6;
    if (t == 0) s_running = 0;
    __syncthreads();
    for (int base = 0; base < N_NODES; base += 1024) {
        int i = base + t;
        int v = (i < N_NODES) ? deg[i] : 0;
        int incl = v;
#pragma unroll
        for (int off = 1; off < 64; off <<= 1) {
            int u = __shfl_up(incl, off, 64);
            if (lane >= off) incl += u;
        }
        if (lane == 63) wsum[wid] = incl;
        __syncthreads();
        int run = s_running;
        if (wid == 0) {
            int wv = (lane < 16) ? wsum[lane] : 0;
            int wi = wv;
#pragma unroll
            for (int off = 1; off < 16; off <<= 1) {
                int u = __shfl_up(wi, off, 64);
                if (lane >= off) wi += u;
            }
            if (lane < 16) wsum[lane] = wi - wv;  // exclusive wave offsets
            if (lane == 15) s_chunk = wi;         // chunk total
        }
        __syncthreads();
        if (i < N_NODES) {
            int excl = run + wsum[wid] + (incl - v);
            row_ptr[i] = excl;
            cursor[i]  = excl;
            inv_deg[i] = 1.0f / (float)(v > 1 ? v : 1);
        }
        __syncthreads();
        if (t == 0) s_running = run + s_chunk;
        __syncthreads();
    }
    if (t == 0) row_ptr[N_NODES] = s_running;
}

__global__ void fill_csr_kernel(const int* __restrict__ src, const int* __restrict__ dst,
                                int* __restrict__ cursor, int* __restrict__ csr_src, int n) {
    int i = blockIdx.x * 256 + threadIdx.x;
    if (i < n) {
        int p = atomicAdd(&cursor[dst[i]], 1);
        csr_src[p] = src[i];
    }
}

// ---------------- mean aggregation (atomic-free gather) ----------------

__global__ void agg_mean_kernel(const float* __restrict__ h, const int* __restrict__ csr_src,
                                const int* __restrict__ row_ptr, const float* __restrict__ inv_deg,
                                float* __restrict__ mean) {
    int node = blockIdx.x * 2 + (threadIdx.x >> 7);
    int f = threadIdx.x & 127;
    if (node >= N_NODES) return;
    int s = row_ptr[node], e = row_ptr[node + 1];
    float acc = 0.f;
    for (int i = s; i < e; ++i) acc += h[(size_t)csr_src[i] * F + f];
    mean[(size_t)node * F + f] = acc * inv_deg[node];
}

// ---------------- fused SAGE layer GEMM ----------------
// out = leaky_relu(A1@W1 + A2@W2 + bias), A: [N,128], W: [128,128]
// BM=64, BN=128, BK=32, 256 threads, 8x4 micro-tile per thread.
__global__ __launch_bounds__(256) void sage_gemm_kernel(
    const float* __restrict__ A1, const float* __restrict__ A2,
    const float* __restrict__ W1, const float* __restrict__ W2,
    const float* __restrict__ bias, float* __restrict__ out) {
    __shared__ float sAT[32 * 68];   // [k][r], pad 68
    __shared__ float sB[32 * 128];
    int t = threadIdx.x;
    int tx = t & 31, ty = t >> 5;    // cols 4*tx, rows ty*8..+7
    int bm0 = blockIdx.x * 64;
    float4 acc[8];
#pragma unroll
    for (int j = 0; j < 8; ++j) acc[j] = make_float4(0.f, 0.f, 0.f, 0.f);

    for (int p = 0; p < 2; ++p) {
        const float* A = p ? A2 : A1;
        const float* W = p ? W2 : W1;
        for (int kt = 0; kt < 4; ++kt) {
            int k0 = kt * 32;
            __syncthreads();
            // stage A chunk (transposed)
#pragma unroll
            for (int i = 0; i < 2; ++i) {
                int f = i * 256 + t;
                int r = f >> 3, c4 = f & 7;
                int n = bm0 + r;
                float4 v = make_float4(0.f, 0.f, 0.f, 0.f);
                if (n < N_NODES) v = *(const float4*)&A[(size_t)n * F + k0 + c4 * 4];
                int kl = c4 * 4;
                sAT[(kl + 0) * 68 + r] = v.x;
                sAT[(kl + 1) * 68 + r] = v.y;
                sAT[(kl + 2) * 68 + r] = v.z;
                sAT[(kl + 3) * 68 + r] = v.w;
            }
            // stage B chunk
#pragma unroll
            for (int i = 0; i < 4; ++i) {
                int f = i * 256 + t;
                int row = f >> 5, c4 = f & 31;
                *(float4*)&sB[row * 128 + c4 * 4] =
                    *(const float4*)&W[(size_t)(k0 + row) * 128 + c4 * 4];
            }
            __syncthreads();
#pragma unroll
            for (int k = 0; k < 32; ++k) {
                float4 b = *(const float4*)&sB[k * 128 + tx * 4];
                float4 a0 = *(const float4*)&sAT[k * 68 + ty * 8];
                float4 a1 = *(const float4*)&sAT[k * 68 + ty * 8 + 4];
                float av[8] = {a0.x, a0.y, a0.z, a0.w, a1.x, a1.y, a1.z, a1.w};
#pragma unroll
                for (int j = 0; j < 8; ++j) {
                    acc[j].x += av[j] * b.x;
                    acc[j].y += av[j] * b.y;
                    acc[j].z += av[j] * b.z;
                    acc[j].w += av[j] * b.w;
                }
            }
        }
    }
    float4 bv = *(const float4*)&bias[tx * 4];
#pragma unroll
    for (int j = 0; j < 8; ++j) {
        int n = bm0 + ty * 8 + j;
        if (n < N_NODES) {
            float4 v;
            v.x = acc[j].x + bv.x; v.y = acc[j].y + bv.y;
            v.z = acc[j].z + bv.z; v.w = acc[j].w + bv.w;
            v.x = v.x > 0.f ? v.x : 0.01f * v.x;
            v.y = v.y > 0.f ? v.y : 0.01f * v.y;
            v.z = v.z > 0.f ? v.z : 0.01f * v.z;
            v.w = v.w > 0.f ? v.w : 0.01f * v.w;
            *(float4*)&out[(size_t)n * F + tx * 4] = v;
        }
    }
}

// ---------------- fused edge MLP ----------------
// per edge: vec = [h[src](128), h[dst](128), ef(1)] ; hid = relu(vec@mw1+mb1) ;
// out = hid@mw2 + mb2. BM=64 edges per block, 256 threads.
__global__ __launch_bounds__(256) void edge_mlp_kernel(
    const float* __restrict__ h, const float* __restrict__ ef,
    const int* __restrict__ src, const int* __restrict__ dst,
    const float* __restrict__ mw1, const float* __restrict__ mb1,
    const float* __restrict__ mw2, const float* __restrict__ mb2,
    float* __restrict__ out) {
    __shared__ float smem[64 * 132];   // union: (sAT 2176 + sB 4096) | hidden 8448
    __shared__ int sid[64], did[64];
    __shared__ float sef[64];
    __shared__ float sW2[256];
    float* sAT = smem;          // 32*68
    float* sB  = smem + 2176;   // 32*128
    float* sHid = smem;         // 64*132

    int t = threadIdx.x;
    int tx = t & 31, ty = t >> 5;
    int e0 = blockIdx.x * 64;
    if (t < 64) {
        sid[t] = src[e0 + t];
        did[t] = dst[e0 + t];
        sef[t] = ef[e0 + t];
    }
    sW2[t] = mw2[t];
    float4 acc[8];
#pragma unroll
    for (int j = 0; j < 8; ++j) acc[j] = make_float4(0.f, 0.f, 0.f, 0.f);

    for (int kt = 0; kt < 8; ++kt) {
        int colbase = (kt & 3) * 32;
        __syncthreads();
        const int* ids = (kt < 4) ? sid : did;
#pragma unroll
        for (int i = 0; i < 2; ++i) {
            int f = i * 256 + t;
            int r = f >> 3, c4 = f & 7;
            int nid = ids[r];
            float4 v = *(const float4*)&h[(size_t)nid * F + colbase + c4 * 4];
            int kl = c4 * 4;
            sAT[(kl + 0) * 68 + r] = v.x;
            sAT[(kl + 1) * 68 + r] = v.y;
            sAT[(kl + 2) * 68 + r] = v.z;
            sAT[(kl + 3) * 68 + r] = v.w;
        }
#pragma unroll
        for (int i = 0; i < 4; ++i) {
            int f = i * 256 + t;
            int row = f >> 5, c4 = f & 31;
            *(float4*)&sB[row * 128 + c4 * 4] =
                *(const float4*)&mw1[(size_t)(kt * 32 + row) * 128 + c4 * 4];
        }
        __syncthreads();
#pragma unroll
        for (int k = 0; k < 32; ++k) {
            float4 b = *(const float4*)&sB[k * 128 + tx * 4];
            float4 a0 = *(const float4*)&sAT[k * 68 + ty * 8];
            float4 a1 = *(const float4*)&sAT[k * 68 + ty * 8 + 4];
            float av[8] = {a0.x, a0.y, a0.z, a0.w, a1.x, a1.y, a1.z, a1.w};
#pragma unroll
            for (int j = 0; j < 8; ++j) {
                acc[j].x += av[j] * b.x;
                acc[j].y += av[j] * b.y;
                acc[j].z += av[j] * b.z;
                acc[j].w += av[j] * b.w;
            }
        }
    }
    // k = 256 term (edge feature) -- mw1 row 256
    float4 w256 = *(const float4*)&mw1[(size_t)256 * 128 + tx * 4];
#pragma unroll
    for (int j = 0; j < 8; ++j) {
        float a = sef[ty * 8 + j];
        acc[j].x += a * w256.x;
        acc[j].y += a * w256.y;
        acc[j].z += a * w256.z;
        acc[j].w += a * w256.w;
    }
    // bias + relu, stash hidden tile in LDS
    float4 b1 = *(const float4*)&mb1[tx * 4];
    __syncthreads();
#pragma unroll
    for (int j = 0; j < 8; ++j) {
        float4 v;
        v.x = fmaxf(acc[j].x + b1.x, 0.f);
        v.y = fmaxf(acc[j].y + b1.y, 0.f);
        v.z = fmaxf(acc[j].z + b1.z, 0.f);
        v.w = fmaxf(acc[j].w + b1.w, 0.f);
        *(float4*)&sHid[(ty * 8 + j) * 132 + tx * 4] = v;
    }
    __syncthreads();
    // second layer: 128 -> 2
    if (t < 128) {
        int e = t >> 1, c2 = t & 1;
        float a2 = mb2[c2];
#pragma unroll 8
        for (int hh = 0; hh < 128; ++hh) a2 += sHid[e * 132 + hh] * sW2[hh * 2 + c2];
        out[(size_t)(e0 + e) * 2 + c2] = a2;
    }
}

// ---------------- launch ----------------

extern "C" void kernel_launch(void* const* d_in, const int* in_sizes, int n_in,
                              void* d_out, int out_size, void* d_ws, size_t ws_size,
                              hipStream_t stream) {
    const float* node_feats = (const float*)d_in[0];
    const float* edge_feats = (const float*)d_in[1];
    const int*   src = (const int*)d_in[2];
    const int*   dst = (const int*)d_in[3];
    const float* ws0 = (const float*)d_in[4];
    const float* wn0 = (const float*)d_in[5];
    const float* b0  = (const float*)d_in[6];
    const float* ws1 = (const float*)d_in[7];
    const float* wn1 = (const float*)d_in[8];
    const float* b1  = (const float*)d_in[9];
    const float* ws2 = (const float*)d_in[10];
    const float* wn2 = (const float*)d_in[11];
    const float* b2  = (const float*)d_in[12];
    const float* mw1 = (const float*)d_in[13];
    const float* mb1 = (const float*)d_in[14];
    const float* mw2 = (const float*)d_in[15];
    const float* mb2 = (const float*)d_in[16];
    float* out = (float*)d_out;

    char* ws = (char*)d_ws;
    size_t off = 0;
    auto alloc = [&](size_t bytes) {
        size_t o = off;
        off += (bytes + 511) & ~(size_t)511;
        return o;
    };
    float* h0   = (float*)(ws + alloc((size_t)N_NODES * F * 4));
    float* h1   = (float*)(ws + alloc((size_t)N_NODES * F * 4));
    float* mean = (float*)(ws + alloc((size_t)N_NODES * F * 4));
    int*   deg  = (int*)  (ws + alloc((size_t)N_NODES * 4));
    float* invd = (float*)(ws + alloc((size_t)N_NODES * 4));
    int*   rowp = (int*)  (ws + alloc(((size_t)N_NODES + 1) * 4));
    int*   cur  = (int*)  (ws + alloc((size_t)N_NODES * 4));
    int*   csrc = (int*)  (ws + alloc((size_t)N_EDGES * 4));

    hipMemsetAsync(deg, 0, (size_t)N_NODES * 4, stream);
    count_deg_kernel<<<(N_EDGES + 255) / 256, 256, 0, stream>>>(dst, deg, N_EDGES);
    scan_kernel<<<1, 1024, 0, stream>>>(deg, rowp, cur, invd);
    fill_csr_kernel<<<(N_EDGES + 255) / 256, 256, 0, stream>>>(src, dst, cur, csrc, N_EDGES);

    const float* hin = node_feats;
    float*       houts[3] = {h0, h1, h0};
    const float* wss[3] = {ws0, ws1, ws2};
    const float* wns[3] = {wn0, wn1, wn2};
    const float* bs[3]  = {b0, b1, b2};
    for (int l = 0; l < 3; ++l) {
        agg_mean_kernel<<<N_NODES / 2, 256, 0, stream>>>(hin, csrc, rowp, invd, mean);
        sage_gemm_kernel<<<(N_NODES + 63) / 64, 256, 0, stream>>>(hin, mean, wss[l], wns[l], bs[l], houts[l]);
        hin = houts[l];
    }
    edge_mlp_kernel<<<N_EDGES / 64, 256, 0, stream>>>(hin, edge_feats, src, dst,
                                                      mw1, mb1, mw2, mb2, out);
}

// Round 2
// 2018.527 us; speedup vs baseline: 1.4096x; 1.4096x over previous
//
#include <hip/hip_runtime.h>
#include <hip/hip_bf16.h>

#define N_NODES 100000
#define N_EDGES 1600000
#define F 128
#define KW 272          // padded K for edge-MLP weights: 256 feats + ef + bias + pad to 17*16
#define TILES_PER_BLOCK 16

typedef short bf16x8 __attribute__((ext_vector_type(8)));
typedef float f32x16 __attribute__((ext_vector_type(16)));

__device__ __forceinline__ short f2bf(float x) {
    unsigned u = __builtin_bit_cast(unsigned, x);
    u += 0x7FFF + ((u >> 16) & 1);          // RNE
    return (short)(u >> 16);
}

// ---------------- CSR build ----------------

__global__ void count_deg_kernel(const int* __restrict__ dst, int* __restrict__ deg, int n) {
    int i = blockIdx.x * 256 + threadIdx.x;
    if (i < n) atomicAdd(&deg[dst[i]], 1);
}

__global__ void scan_kernel(const int* __restrict__ deg, int* __restrict__ row_ptr,
                            int* __restrict__ cursor, float* __restrict__ inv_deg) {
    __shared__ int wsum[16];
    __shared__ int s_chunk;
    __shared__ int s_running;
    int t = threadIdx.x;
    int lane = t & 63, wid = t >> 6;
    if (t == 0) s_running = 0;
    __syncthreads();
    for (int base = 0; base < N_NODES; base += 1024) {
        int i = base + t;
        int v = (i < N_NODES) ? deg[i] : 0;
        int incl = v;
#pragma unroll
        for (int off = 1; off < 64; off <<= 1) {
            int u = __shfl_up(incl, off, 64);
            if (lane >= off) incl += u;
        }
        if (lane == 63) wsum[wid] = incl;
        __syncthreads();
        int run = s_running;
        if (wid == 0) {
            int wv = (lane < 16) ? wsum[lane] : 0;
            int wi = wv;
#pragma unroll
            for (int off = 1; off < 16; off <<= 1) {
                int u = __shfl_up(wi, off, 64);
                if (lane >= off) wi += u;
            }
            if (lane < 16) wsum[lane] = wi - wv;
            if (lane == 15) s_chunk = wi;
        }
        __syncthreads();
        if (i < N_NODES) {
            int excl = run + wsum[wid] + (incl - v);
            row_ptr[i] = excl;
            cursor[i]  = excl;
            inv_deg[i] = 1.0f / (float)(v > 1 ? v : 1);
        }
        __syncthreads();
        if (t == 0) s_running = run + s_chunk;
        __syncthreads();
    }
    if (t == 0) row_ptr[N_NODES] = s_running;
}

__global__ void fill_csr_kernel(const int* __restrict__ src, const int* __restrict__ dst,
                                int* __restrict__ cursor, int* __restrict__ csr_src, int n) {
    int i = blockIdx.x * 256 + threadIdx.x;
    if (i < n) {
        int p = atomicAdd(&cursor[dst[i]], 1);
        csr_src[p] = src[i];
    }
}

// ---------------- mean aggregation ----------------

__global__ void agg_mean_kernel(const float* __restrict__ h, const int* __restrict__ csr_src,
                                const int* __restrict__ row_ptr, const float* __restrict__ inv_deg,
                                float* __restrict__ mean) {
    int node = blockIdx.x * 2 + (threadIdx.x >> 7);
    int f = threadIdx.x & 127;
    if (node >= N_NODES) return;
    int s = row_ptr[node], e = row_ptr[node + 1];
    float acc = 0.f;
    for (int i = s; i < e; ++i) acc += h[(size_t)csr_src[i] * F + f];
    mean[(size_t)node * F + f] = acc * inv_deg[node];
}

// ---------------- fused SAGE layer GEMM (fp32, unchanged) ----------------

__global__ __launch_bounds__(256) void sage_gemm_kernel(
    const float* __restrict__ A1, const float* __restrict__ A2,
    const float* __restrict__ W1, const float* __restrict__ W2,
    const float* __restrict__ bias, float* __restrict__ out) {
    __shared__ float sAT[32 * 68];
    __shared__ float sB[32 * 128];
    int t = threadIdx.x;
    int tx = t & 31, ty = t >> 5;
    int bm0 = blockIdx.x * 64;
    float4 acc[8];
#pragma unroll
    for (int j = 0; j < 8; ++j) acc[j] = make_float4(0.f, 0.f, 0.f, 0.f);

    for (int p = 0; p < 2; ++p) {
        const float* A = p ? A2 : A1;
        const float* W = p ? W2 : W1;
        for (int kt = 0; kt < 4; ++kt) {
            int k0 = kt * 32;
            __syncthreads();
#pragma unroll
            for (int i = 0; i < 2; ++i) {
                int f = i * 256 + t;
                int r = f >> 3, c4 = f & 7;
                int n = bm0 + r;
                float4 v = make_float4(0.f, 0.f, 0.f, 0.f);
                if (n < N_NODES) v = *(const float4*)&A[(size_t)n * F + k0 + c4 * 4];
                int kl = c4 * 4;
                sAT[(kl + 0) * 68 + r] = v.x;
                sAT[(kl + 1) * 68 + r] = v.y;
                sAT[(kl + 2) * 68 + r] = v.z;
                sAT[(kl + 3) * 68 + r] = v.w;
            }
#pragma unroll
            for (int i = 0; i < 4; ++i) {
                int f = i * 256 + t;
                int row = f >> 5, c4 = f & 31;
                *(float4*)&sB[row * 128 + c4 * 4] =
                    *(const float4*)&W[(size_t)(k0 + row) * 128 + c4 * 4];
            }
            __syncthreads();
#pragma unroll
            for (int k = 0; k < 32; ++k) {
                float4 b = *(const float4*)&sB[k * 128 + tx * 4];
                float4 a0 = *(const float4*)&sAT[k * 68 + ty * 8];
                float4 a1 = *(const float4*)&sAT[k * 68 + ty * 8 + 4];
                float av[8] = {a0.x, a0.y, a0.z, a0.w, a1.x, a1.y, a1.z, a1.w};
#pragma unroll
                for (int j = 0; j < 8; ++j) {
                    acc[j].x += av[j] * b.x;
                    acc[j].y += av[j] * b.y;
                    acc[j].z += av[j] * b.z;
                    acc[j].w += av[j] * b.w;
                }
            }
        }
    }
    float4 bv = *(const float4*)&bias[tx * 4];
#pragma unroll
    for (int j = 0; j < 8; ++j) {
        int n = bm0 + ty * 8 + j;
        if (n < N_NODES) {
            float4 v;
            v.x = acc[j].x + bv.x; v.y = acc[j].y + bv.y;
            v.z = acc[j].z + bv.z; v.w = acc[j].w + bv.w;
            v.x = v.x > 0.f ? v.x : 0.01f * v.x;
            v.y = v.y > 0.f ? v.y : 0.01f * v.y;
            v.z = v.z > 0.f ? v.z : 0.01f * v.z;
            v.w = v.w > 0.f ? v.w : 0.01f * v.w;
            *(float4*)&out[(size_t)n * F + tx * 4] = v;
        }
    }
}

// ---------------- prep: fp32 -> bf16 ----------------

__global__ void convert_h_kernel(const float* __restrict__ in, ushort* __restrict__ out) {
    int idx = (blockIdx.x * 256 + threadIdx.x) * 8;
    float4 a = *(const float4*)&in[idx];
    float4 b = *(const float4*)&in[idx + 4];
    ushort o[8];
    o[0] = (ushort)f2bf(a.x); o[1] = (ushort)f2bf(a.y);
    o[2] = (ushort)f2bf(a.z); o[3] = (ushort)f2bf(a.w);
    o[4] = (ushort)f2bf(b.x); o[5] = (ushort)f2bf(b.y);
    o[6] = (ushort)f2bf(b.z); o[7] = (ushort)f2bf(b.w);
    *(uint4*)&out[idx] = *(uint4*)o;
}

// Build A-operand weights for edge MLP: aw[h][k], h=0..127, k=0..KW-1 (bf16)
//   k<256   : mw1[k][h]
//   k==256  : mw1[256][h]   (edge-feature row)
//   k==257  : mb1[h]        (bias row, B supplies 1.0)
//   else    : 0
__global__ void prep_w_kernel(const float* __restrict__ mw1, const float* __restrict__ mb1,
                              ushort* __restrict__ aw) {
    int idx = blockIdx.x * 256 + threadIdx.x;
    if (idx >= 128 * KW) return;
    int h = idx / KW;
    int k = idx - h * KW;
    float v = 0.f;
    if (k < 257) v = mw1[(size_t)k * 128 + h];
    else if (k == 257) v = mb1[h];
    aw[idx] = (ushort)f2bf(v);
}

// ---------------- edge MLP via MFMA ----------------
// C[h][e] = sum_k aw[h][k] * B[k][e];  B[k][e] = [h_src | h_dst | ef | 1] per edge.
// Wave w owns hidden rows 32w..32w+31 (A frags persistent in regs).
// Lane: col = edge = lane&31; B frags gathered straight from global (bf16 rows).
__global__ __launch_bounds__(256) void edge_mlp_mfma(
    const ushort* __restrict__ hb, const ushort* __restrict__ aw,
    const float* __restrict__ ef,
    const int* __restrict__ src, const int* __restrict__ dst,
    const float* __restrict__ mw2, const float* __restrict__ mb2,
    float* __restrict__ out) {
    __shared__ float sPart[32][2][8];
    int t = threadIdx.x;
    int lane = t & 63, w = t >> 6;
    int l31 = lane & 31, hf = lane >> 5;

    // persistent A fragments (17 k-steps x 8 bf16)
    bf16x8 afrag[17];
    const ushort* ap = aw + (size_t)(w * 32 + l31) * KW + hf * 8;
#pragma unroll
    for (int f = 0; f < 17; ++f) afrag[f] = *(const bf16x8*)(ap + f * 16);

    // per-lane second-layer weights for this lane's 16 hidden rows
    float w2c0[16], w2c1[16];
#pragma unroll
    for (int r = 0; r < 16; ++r) {
        int row = w * 32 + (r & 3) + 8 * (r >> 2) + 4 * hf;
        float2 v = *(const float2*)&mw2[row * 2];
        w2c0[r] = v.x; w2c1[r] = v.y;
    }

    int e_base = blockIdx.x * (TILES_PER_BLOCK * 32);
    for (int tile = 0; tile < TILES_PER_BLOCK; ++tile) {
        int e0 = e_base + tile * 32;
        int e = e0 + l31;
        int is = src[e], id = dst[e];
        float efv = ef[e];
        const ushort* bs = hb + (size_t)is * F + hf * 8;
        const ushort* bd = hb + (size_t)id * F + hf * 8;

        f32x16 acc;
#pragma unroll
        for (int r = 0; r < 16; ++r) acc[r] = 0.f;

#pragma unroll
        for (int f = 0; f < 8; ++f) {
            bf16x8 b = *(const bf16x8*)(bs + f * 16);
            acc = __builtin_amdgcn_mfma_f32_32x32x16_bf16(afrag[f], b, acc, 0, 0, 0);
        }
#pragma unroll
        for (int f = 0; f < 8; ++f) {
            bf16x8 b = *(const bf16x8*)(bd + f * 16);
            acc = __builtin_amdgcn_mfma_f32_32x32x16_bf16(afrag[8 + f], b, acc, 0, 0, 0);
        }
        // k-step 16: rows 256 (ef) and 257 (bias*1.0); zeros elsewhere
        bf16x8 bx;
#pragma unroll
        for (int j = 0; j < 8; ++j) bx[j] = 0;
        if (hf == 0) { bx[0] = f2bf(efv); bx[1] = (short)0x3F80; }
        acc = __builtin_amdgcn_mfma_f32_32x32x16_bf16(afrag[16], bx, acc, 0, 0, 0);

        // relu + per-lane partial of second layer
        float p0 = 0.f, p1 = 0.f;
#pragma unroll
        for (int r = 0; r < 16; ++r) {
            float h = fmaxf(acc[r], 0.f);
            p0 += h * w2c0[r];
            p1 += h * w2c1[r];
        }
        sPart[l31][0][w * 2 + hf] = p0;
        sPart[l31][1][w * 2 + hf] = p1;
        __syncthreads();
        if (t < 64) {
            float4 a = *(const float4*)&sPart[t >> 1][t & 1][0];
            float4 b = *(const float4*)&sPart[t >> 1][t & 1][4];
            float s = a.x + a.y + a.z + a.w + b.x + b.y + b.z + b.w + mb2[t & 1];
            out[(size_t)e0 * 2 + t] = s;
        }
        __syncthreads();
    }
}

// ---------------- launch ----------------

extern "C" void kernel_launch(void* const* d_in, const int* in_sizes, int n_in,
                              void* d_out, int out_size, void* d_ws, size_t ws_size,
                              hipStream_t stream) {
    const float* node_feats = (const float*)d_in[0];
    const float* edge_feats = (const float*)d_in[1];
    const int*   src = (const int*)d_in[2];
    const int*   dst = (const int*)d_in[3];
    const float* ws0 = (const float*)d_in[4];
    const float* wn0 = (const float*)d_in[5];
    const float* b0  = (const float*)d_in[6];
    const float* ws1 = (const float*)d_in[7];
    const float* wn1 = (const float*)d_in[8];
    const float* b1  = (const float*)d_in[9];
    const float* ws2 = (const float*)d_in[10];
    const float* wn2 = (const float*)d_in[11];
    const float* b2  = (const float*)d_in[12];
    const float* mw1 = (const float*)d_in[13];
    const float* mb1 = (const float*)d_in[14];
    const float* mw2 = (const float*)d_in[15];
    const float* mb2 = (const float*)d_in[16];
    float* out = (float*)d_out;

    char* ws = (char*)d_ws;
    size_t off = 0;
    auto alloc = [&](size_t bytes) {
        size_t o = off;
        off += (bytes + 511) & ~(size_t)511;
        return o;
    };
    float* h0   = (float*)(ws + alloc((size_t)N_NODES * F * 4));
    float* h1   = (float*)(ws + alloc((size_t)N_NODES * F * 4));
    float* mean = (float*)(ws + alloc((size_t)N_NODES * F * 4));
    int*   deg  = (int*)  (ws + alloc((size_t)N_NODES * 4));
    float* invd = (float*)(ws + alloc((size_t)N_NODES * 4));
    int*   rowp = (int*)  (ws + alloc(((size_t)N_NODES + 1) * 4));
    int*   cur  = (int*)  (ws + alloc((size_t)N_NODES * 4));
    int*   csrc = (int*)  (ws + alloc((size_t)N_EDGES * 4));
    ushort* aw  = (ushort*)(ws + alloc((size_t)128 * KW * 2));
    ushort* hb  = (ushort*)mean;   // alias: mean is dead after the last SAGE gemm

    hipMemsetAsync(deg, 0, (size_t)N_NODES * 4, stream);
    count_deg_kernel<<<(N_EDGES + 255) / 256, 256, 0, stream>>>(dst, deg, N_EDGES);
    scan_kernel<<<1, 1024, 0, stream>>>(deg, rowp, cur, invd);
    fill_csr_kernel<<<(N_EDGES + 255) / 256, 256, 0, stream>>>(src, dst, cur, csrc, N_EDGES);
    prep_w_kernel<<<(128 * KW + 255) / 256, 256, 0, stream>>>(mw1, mb1, aw);

    const float* hin = node_feats;
    float*       houts[3] = {h0, h1, h0};
    const float* wss[3] = {ws0, ws1, ws2};
    const float* wns[3] = {wn0, wn1, wn2};
    const float* bs[3]  = {b0, b1, b2};
    for (int l = 0; l < 3; ++l) {
        agg_mean_kernel<<<N_NODES / 2, 256, 0, stream>>>(hin, csrc, rowp, invd, mean);
        sage_gemm_kernel<<<(N_NODES + 63) / 64, 256, 0, stream>>>(hin, mean, wss[l], wns[l], bs[l], houts[l]);
        hin = houts[l];
    }
    // h3 (in h0) -> bf16, into the dead mean buffer
    convert_h_kernel<<<(N_NODES * F / 8 + 255) / 256, 256, 0, stream>>>(h0, hb);

    edge_mlp_mfma<<<N_EDGES / (TILES_PER_BLOCK * 32), 256, 0, stream>>>(
        hb, aw, edge_feats, src, dst, mw2, mb2, out);
}

// Round 3
// 1422.172 us; speedup vs baseline: 2.0007x; 1.4193x over previous
//
#include <hip/hip_runtime.h>
#include <hip/hip_bf16.h>

#define N_NODES 100000
#define N_EDGES 1600000
#define F 128
#define KW 272          // padded K: 17 frags x 16

typedef short bf16x8 __attribute__((ext_vector_type(8)));
typedef float f32x16 __attribute__((ext_vector_type(16)));

__device__ __forceinline__ short f2bf(float x) {
    unsigned u = __builtin_bit_cast(unsigned, x);
    u += 0x7FFF + ((u >> 16) & 1);          // RNE
    return (short)(u >> 16);
}
__device__ __forceinline__ float bflo(unsigned u) {
    return __builtin_bit_cast(float, u << 16);
}
__device__ __forceinline__ float bfhi(unsigned u) {
    return __builtin_bit_cast(float, u & 0xFFFF0000u);
}

// ---------------- CSR build ----------------

__global__ void count_deg_kernel(const int* __restrict__ dst, int* __restrict__ deg, int n) {
    int i = blockIdx.x * 256 + threadIdx.x;
    if (i < n) atomicAdd(&deg[dst[i]], 1);
}

__global__ void scan_kernel(const int* __restrict__ deg, int* __restrict__ row_ptr,
                            int* __restrict__ cursor, float* __restrict__ inv_deg) {
    __shared__ int wsum[16];
    __shared__ int s_chunk;
    __shared__ int s_running;
    int t = threadIdx.x;
    int lane = t & 63, wid = t >> 6;
    if (t == 0) s_running = 0;
    __syncthreads();
    for (int base = 0; base < N_NODES; base += 1024) {
        int i = base + t;
        int v = (i < N_NODES) ? deg[i] : 0;
        int incl = v;
#pragma unroll
        for (int off = 1; off < 64; off <<= 1) {
            int u = __shfl_up(incl, off, 64);
            if (lane >= off) incl += u;
        }
        if (lane == 63) wsum[wid] = incl;
        __syncthreads();
        int run = s_running;
        if (wid == 0) {
            int wv = (lane < 16) ? wsum[lane] : 0;
            int wi = wv;
#pragma unroll
            for (int off = 1; off < 16; off <<= 1) {
                int u = __shfl_up(wi, off, 64);
                if (lane >= off) wi += u;
            }
            if (lane < 16) wsum[lane] = wi - wv;
            if (lane == 15) s_chunk = wi;
        }
        __syncthreads();
        if (i < N_NODES) {
            int excl = run + wsum[wid] + (incl - v);
            row_ptr[i] = excl;
            cursor[i]  = excl;
            inv_deg[i] = 1.0f / (float)(v > 1 ? v : 1);
        }
        __syncthreads();
        if (t == 0) s_running = run + s_chunk;
        __syncthreads();
    }
    if (t == 0) row_ptr[N_NODES] = s_running;
}

__global__ void fill_csr_kernel(const int* __restrict__ src, const int* __restrict__ dst,
                                int* __restrict__ cursor, int* __restrict__ csr_src, int n) {
    int i = blockIdx.x * 256 + threadIdx.x;
    if (i < n) {
        int p = atomicAdd(&cursor[dst[i]], 1);
        csr_src[p] = src[i];
    }
}

// ---------------- fp32 -> bf16 convert ----------------

__global__ void convert_bf16_kernel(const float* __restrict__ in, ushort* __restrict__ out) {
    int idx = (blockIdx.x * 256 + threadIdx.x) * 8;
    float4 a = *(const float4*)&in[idx];
    float4 b = *(const float4*)&in[idx + 4];
    ushort o[8];
    o[0] = (ushort)f2bf(a.x); o[1] = (ushort)f2bf(a.y);
    o[2] = (ushort)f2bf(a.z); o[3] = (ushort)f2bf(a.w);
    o[4] = (ushort)f2bf(b.x); o[5] = (ushort)f2bf(b.y);
    o[6] = (ushort)f2bf(b.z); o[7] = (ushort)f2bf(b.w);
    *(uint4*)&out[idx] = *(uint4*)o;
}

// ---------------- weight prep (A operand, weight-stationary) ----------------
// sage: aw[h][k]: k<128: ws[k][h]; k<256: wn[k-128][h]; k==256: bias[h]; else 0
__global__ void prep_sage_w(const float* __restrict__ wsx, const float* __restrict__ wnx,
                            const float* __restrict__ b, ushort* __restrict__ aw) {
    int idx = blockIdx.x * 256 + threadIdx.x;
    if (idx >= 128 * KW) return;
    int h = idx / KW;
    int k = idx - h * KW;
    float v = 0.f;
    if (k < 128) v = wsx[(size_t)k * 128 + h];
    else if (k < 256) v = wnx[(size_t)(k - 128) * 128 + h];
    else if (k == 256) v = b[h];
    aw[idx] = (ushort)f2bf(v);
}

// mlp: k<257: mw1[k][h]; k==257: mb1[h]; else 0
__global__ void prep_mlp_w(const float* __restrict__ mw1, const float* __restrict__ mb1,
                           ushort* __restrict__ aw) {
    int idx = blockIdx.x * 256 + threadIdx.x;
    if (idx >= 128 * KW) return;
    int h = idx / KW;
    int k = idx - h * KW;
    float v = 0.f;
    if (k < 257) v = mw1[(size_t)k * 128 + h];
    else if (k == 257) v = mb1[h];
    aw[idx] = (ushort)f2bf(v);
}

// ---------------- mean aggregation (bf16 in/out, fp32 accum) ----------------
// one wave per node; lane owns 2 feats (uint = 2 bf16)
__global__ __launch_bounds__(256) void agg_mean_bf16(
    const ushort* __restrict__ h, const int* __restrict__ csr_src,
    const int* __restrict__ row_ptr, const float* __restrict__ inv_deg,
    ushort* __restrict__ mean) {
    int node = blockIdx.x * 4 + (threadIdx.x >> 6);
    int lane = threadIdx.x & 63;
    int s = row_ptr[node], e = row_ptr[node + 1];
    float a0 = 0.f, a1 = 0.f;
    for (int i = s; i < e; ++i) {
        int nid = csr_src[i];
        unsigned u = *(const unsigned*)(h + (size_t)nid * F + lane * 2);
        a0 += bflo(u);
        a1 += bfhi(u);
    }
    float iv = inv_deg[node];
    ushort o[2] = {(ushort)f2bf(a0 * iv), (ushort)f2bf(a1 * iv)};
    *(unsigned*)(mean + (size_t)node * F + lane * 2) = *(unsigned*)o;
}

// ---------------- SAGE layer via MFMA (weight-stationary, no LDS/barriers) ----
// C[hid][node] = sum_k aw[hid][k] * X[k][node], X = [h | mean | 1]
// wave w: hidden rows 32w..32w+31; lane col = node (dense, coalesced gathers)
#define STILE 8
__global__ __launch_bounds__(256) void sage_gemm_mfma(
    const ushort* __restrict__ hb, const ushort* __restrict__ mb,
    const ushort* __restrict__ aw, ushort* __restrict__ hout) {
    int t = threadIdx.x;
    int lane = t & 63, w = t >> 6;
    int l31 = lane & 31, hf = lane >> 5;

    bf16x8 afrag[17];
    const ushort* ap = aw + (size_t)(w * 32 + l31) * KW + hf * 8;
#pragma unroll
    for (int f = 0; f < 17; ++f) afrag[f] = *(const bf16x8*)(ap + f * 16);

    int tile0 = blockIdx.x * STILE;
    for (int tt = 0; tt < STILE; ++tt) {
        int tile = tile0 + tt;
        if (tile >= N_NODES / 32) break;
        int n = tile * 32 + l31;
        const ushort* bs = hb + (size_t)n * F + hf * 8;
        const ushort* bd = mb + (size_t)n * F + hf * 8;

        f32x16 acc1, acc2;
#pragma unroll
        for (int r = 0; r < 16; ++r) { acc1[r] = 0.f; acc2[r] = 0.f; }
#pragma unroll
        for (int f = 0; f < 8; ++f) {
            bf16x8 b = *(const bf16x8*)(bs + f * 16);
            acc1 = __builtin_amdgcn_mfma_f32_32x32x16_bf16(afrag[f], b, acc1, 0, 0, 0);
        }
#pragma unroll
        for (int f = 0; f < 8; ++f) {
            bf16x8 b = *(const bf16x8*)(bd + f * 16);
            acc2 = __builtin_amdgcn_mfma_f32_32x32x16_bf16(afrag[8 + f], b, acc2, 0, 0, 0);
        }
        bf16x8 bx;
#pragma unroll
        for (int j = 0; j < 8; ++j) bx[j] = 0;
        if (hf == 0) bx[0] = (short)0x3F80;   // k=256: bias row * 1.0
        acc2 = __builtin_amdgcn_mfma_f32_32x32x16_bf16(afrag[16], bx, acc2, 0, 0, 0);

        // leaky-relu + pack + store: reg r -> hidden w*32 + (r&3) + 8*(r>>2) + 4*hf
#pragma unroll
        for (int g = 0; g < 4; ++g) {
            ushort o4[4];
#pragma unroll
            for (int j = 0; j < 4; ++j) {
                float v = acc1[g * 4 + j] + acc2[g * 4 + j];
                v = v > 0.f ? v : 0.01f * v;
                o4[j] = (ushort)f2bf(v);
            }
            *(uint2*)(hout + (size_t)n * F + w * 32 + g * 8 + hf * 4) = *(uint2*)o4;
        }
    }
}

// ---------------- edge MLP via MFMA (single barrier per 512-edge block) ------
__global__ __launch_bounds__(256) void edge_mlp_mfma(
    const ushort* __restrict__ hb, const ushort* __restrict__ aw,
    const float* __restrict__ ef,
    const int* __restrict__ src, const int* __restrict__ dst,
    const float* __restrict__ mw2, const float* __restrict__ mb2,
    float* __restrict__ out) {
    __shared__ int sid[512], did[512];
    __shared__ float sef[512];
    __shared__ float2 sP[16][4][32];
    int t = threadIdx.x;
    int lane = t & 63, w = t >> 6;
    int l31 = lane & 31, hf = lane >> 5;
    int e_base = blockIdx.x * 512;

#pragma unroll
    for (int i = 0; i < 2; ++i) {
        int idx = i * 256 + t;
        sid[idx] = src[e_base + idx];
        did[idx] = dst[e_base + idx];
        sef[idx] = ef[e_base + idx];
    }

    bf16x8 afrag[17];
    const ushort* ap = aw + (size_t)(w * 32 + l31) * KW + hf * 8;
#pragma unroll
    for (int f = 0; f < 17; ++f) afrag[f] = *(const bf16x8*)(ap + f * 16);

    float w2c0[16], w2c1[16];
#pragma unroll
    for (int r = 0; r < 16; ++r) {
        int row = w * 32 + (r & 3) + 8 * (r >> 2) + 4 * hf;
        float2 v = *(const float2*)&mw2[row * 2];
        w2c0[r] = v.x; w2c1[r] = v.y;
    }
    __syncthreads();

    for (int tile = 0; tile < 16; ++tile) {
        int is = sid[tile * 32 + l31];
        int id = did[tile * 32 + l31];
        float efv = sef[tile * 32 + l31];
        const ushort* bs = hb + (size_t)is * F + hf * 8;
        const ushort* bd = hb + (size_t)id * F + hf * 8;

        f32x16 acc1, acc2;
#pragma unroll
        for (int r = 0; r < 16; ++r) { acc1[r] = 0.f; acc2[r] = 0.f; }
#pragma unroll
        for (int f = 0; f < 8; ++f) {
            bf16x8 b = *(const bf16x8*)(bs + f * 16);
            acc1 = __builtin_amdgcn_mfma_f32_32x32x16_bf16(afrag[f], b, acc1, 0, 0, 0);
        }
#pragma unroll
        for (int f = 0; f < 8; ++f) {
            bf16x8 b = *(const bf16x8*)(bd + f * 16);
            acc2 = __builtin_amdgcn_mfma_f32_32x32x16_bf16(afrag[8 + f], b, acc2, 0, 0, 0);
        }
        bf16x8 bx;
#pragma unroll
        for (int j = 0; j < 8; ++j) bx[j] = 0;
        if (hf == 0) { bx[0] = f2bf(efv); bx[1] = (short)0x3F80; }
        acc2 = __builtin_amdgcn_mfma_f32_32x32x16_bf16(afrag[16], bx, acc2, 0, 0, 0);

        float p0 = 0.f, p1 = 0.f;
#pragma unroll
        for (int r = 0; r < 16; ++r) {
            float h = fmaxf(acc1[r] + acc2[r], 0.f);
            p0 += h * w2c0[r];
            p1 += h * w2c1[r];
        }
        p0 += __shfl_xor(p0, 32, 64);
        p1 += __shfl_xor(p1, 32, 64);
        if (hf == 0) sP[tile][w][l31] = make_float2(p0, p1);
    }
    __syncthreads();

    // 512 edges x 2 classes; thread t writes edges 2t, 2t+1 as one float4
    float b2a = mb2[0], b2b = mb2[1];
    float4 o;
    {
        int e = 2 * t, tl = e >> 5, l = e & 31;
        float q0 = b2a, q1 = b2b;
#pragma unroll
        for (int ww = 0; ww < 4; ++ww) { float2 p = sP[tl][ww][l]; q0 += p.x; q1 += p.y; }
        o.x = q0; o.y = q1;
    }
    {
        int e = 2 * t + 1, tl = e >> 5, l = e & 31;
        float q0 = b2a, q1 = b2b;
#pragma unroll
        for (int ww = 0; ww < 4; ++ww) { float2 p = sP[tl][ww][l]; q0 += p.x; q1 += p.y; }
        o.z = q0; o.w = q1;
    }
    *(float4*)&out[(size_t)(e_base + 2 * t) * 2] = o;
}

// ---------------- launch ----------------

extern "C" void kernel_launch(void* const* d_in, const int* in_sizes, int n_in,
                              void* d_out, int out_size, void* d_ws, size_t ws_size,
                              hipStream_t stream) {
    const float* node_feats = (const float*)d_in[0];
    const float* edge_feats = (const float*)d_in[1];
    const int*   src = (const int*)d_in[2];
    const int*   dst = (const int*)d_in[3];
    const float* ws0 = (const float*)d_in[4];
    const float* wn0 = (const float*)d_in[5];
    const float* b0  = (const float*)d_in[6];
    const float* ws1 = (const float*)d_in[7];
    const float* wn1 = (const float*)d_in[8];
    const float* b1  = (const float*)d_in[9];
    const float* ws2 = (const float*)d_in[10];
    const float* wn2 = (const float*)d_in[11];
    const float* b2  = (const float*)d_in[12];
    const float* mw1 = (const float*)d_in[13];
    const float* mb1 = (const float*)d_in[14];
    const float* mw2 = (const float*)d_in[15];
    const float* mb2 = (const float*)d_in[16];
    float* out = (float*)d_out;

    char* ws = (char*)d_ws;
    size_t off = 0;
    auto alloc = [&](size_t bytes) {
        size_t o = off;
        off += (bytes + 511) & ~(size_t)511;
        return o;
    };
    ushort* nfb  = (ushort*)(ws + alloc((size_t)N_NODES * F * 2));
    ushort* hb0  = (ushort*)(ws + alloc((size_t)N_NODES * F * 2));
    ushort* hb1  = (ushort*)(ws + alloc((size_t)N_NODES * F * 2));
    ushort* meanb= (ushort*)(ws + alloc((size_t)N_NODES * F * 2));
    int*   deg  = (int*)  (ws + alloc((size_t)N_NODES * 4));
    float* invd = (float*)(ws + alloc((size_t)N_NODES * 4));
    int*   rowp = (int*)  (ws + alloc(((size_t)N_NODES + 1) * 4));
    int*   cur  = (int*)  (ws + alloc((size_t)N_NODES * 4));
    int*   csrc = (int*)  (ws + alloc((size_t)N_EDGES * 4));
    ushort* aw0 = (ushort*)(ws + alloc((size_t)128 * KW * 2));
    ushort* aw1 = (ushort*)(ws + alloc((size_t)128 * KW * 2));
    ushort* aw2 = (ushort*)(ws + alloc((size_t)128 * KW * 2));
    ushort* awm = (ushort*)(ws + alloc((size_t)128 * KW * 2));

    hipMemsetAsync(deg, 0, (size_t)N_NODES * 4, stream);
    count_deg_kernel<<<(N_EDGES + 255) / 256, 256, 0, stream>>>(dst, deg, N_EDGES);
    scan_kernel<<<1, 1024, 0, stream>>>(deg, rowp, cur, invd);
    fill_csr_kernel<<<(N_EDGES + 255) / 256, 256, 0, stream>>>(src, dst, cur, csrc, N_EDGES);

    int pgrid = (128 * KW + 255) / 256;
    prep_sage_w<<<pgrid, 256, 0, stream>>>(ws0, wn0, b0, aw0);
    prep_sage_w<<<pgrid, 256, 0, stream>>>(ws1, wn1, b1, aw1);
    prep_sage_w<<<pgrid, 256, 0, stream>>>(ws2, wn2, b2, aw2);
    prep_mlp_w<<<pgrid, 256, 0, stream>>>(mw1, mb1, awm);
    convert_bf16_kernel<<<(N_NODES * F / 8 + 255) / 256, 256, 0, stream>>>(node_feats, nfb);

    int ggrid = (N_NODES / 32 + STILE - 1) / STILE;
    const ushort* hin = nfb;
    ushort* houts[3] = {hb0, hb1, hb0};
    const ushort* aws[3] = {aw0, aw1, aw2};
    for (int l = 0; l < 3; ++l) {
        agg_mean_bf16<<<N_NODES / 4, 256, 0, stream>>>(hin, csrc, rowp, invd, meanb);
        sage_gemm_mfma<<<ggrid, 256, 0, stream>>>(hin, meanb, aws[l], houts[l]);
        hin = houts[l];
    }
    edge_mlp_mfma<<<N_EDGES / 512, 256, 0, stream>>>(hb0, awm, edge_feats, src, dst,
                                                     mw2, mb2, out);
}

// Round 4
// 895.396 us; speedup vs baseline: 3.1778x; 1.5883x over previous
//
#include <hip/hip_runtime.h>
#include <hip/hip_bf16.h>

#define N_NODES 100000
#define N_EDGES 1600000
#define F 128
#define KW 272          // sage padded K: 17 frags x 16
#define KS 144          // zs padded K: 128 + bias -> 9 frags
#define KD 128          // zd K: 8 frags
#define EROUNDS 8       // edge kernel: 16 edges/block/round

typedef short bf16x8 __attribute__((ext_vector_type(8)));
typedef float f32x16 __attribute__((ext_vector_type(16)));
typedef _Float16 half8 __attribute__((ext_vector_type(8)));
typedef _Float16 half4 __attribute__((ext_vector_type(4)));

__device__ __forceinline__ short f2bf(float x) {
    unsigned u = __builtin_bit_cast(unsigned, x);
    u += 0x7FFF + ((u >> 16) & 1);          // RNE
    return (short)(u >> 16);
}
__device__ __forceinline__ float bflo(unsigned u) {
    return __builtin_bit_cast(float, u << 16);
}
__device__ __forceinline__ float bfhi(unsigned u) {
    return __builtin_bit_cast(float, u & 0xFFFF0000u);
}

// ---------------- CSR build ----------------

__global__ void count_deg_kernel(const int* __restrict__ dst, int* __restrict__ deg, int n) {
    int i = blockIdx.x * 256 + threadIdx.x;
    if (i < n) atomicAdd(&deg[dst[i]], 1);
}

__global__ void scan_kernel(const int* __restrict__ deg, int* __restrict__ row_ptr,
                            int* __restrict__ cursor, float* __restrict__ inv_deg) {
    __shared__ int wsum[16];
    __shared__ int s_chunk;
    __shared__ int s_running;
    int t = threadIdx.x;
    int lane = t & 63, wid = t >> 6;
    if (t == 0) s_running = 0;
    __syncthreads();
    for (int base = 0; base < N_NODES; base += 1024) {
        int i = base + t;
        int v = (i < N_NODES) ? deg[i] : 0;
        int incl = v;
#pragma unroll
        for (int off = 1; off < 64; off <<= 1) {
            int u = __shfl_up(incl, off, 64);
            if (lane >= off) incl += u;
        }
        if (lane == 63) wsum[wid] = incl;
        __syncthreads();
        int run = s_running;
        if (wid == 0) {
            int wv = (lane < 16) ? wsum[lane] : 0;
            int wi = wv;
#pragma unroll
            for (int off = 1; off < 16; off <<= 1) {
                int u = __shfl_up(wi, off, 64);
                if (lane >= off) wi += u;
            }
            if (lane < 16) wsum[lane] = wi - wv;
            if (lane == 15) s_chunk = wi;
        }
        __syncthreads();
        if (i < N_NODES) {
            int excl = run + wsum[wid] + (incl - v);
            row_ptr[i] = excl;
            cursor[i]  = excl;
            inv_deg[i] = 1.0f / (float)(v > 1 ? v : 1);
        }
        __syncthreads();
        if (t == 0) s_running = run + s_chunk;
        __syncthreads();
    }
    if (t == 0) row_ptr[N_NODES] = s_running;
}

__global__ void fill_csr_kernel(const int* __restrict__ src, const int* __restrict__ dst,
                                int* __restrict__ cursor, int* __restrict__ csr_src, int n) {
    int i = blockIdx.x * 256 + threadIdx.x;
    if (i < n) {
        int p = atomicAdd(&cursor[dst[i]], 1);
        csr_src[p] = src[i];
    }
}

// ---------------- fp32 -> bf16 convert ----------------

__global__ void convert_bf16_kernel(const float* __restrict__ in, ushort* __restrict__ out) {
    int idx = (blockIdx.x * 256 + threadIdx.x) * 8;
    float4 a = *(const float4*)&in[idx];
    float4 b = *(const float4*)&in[idx + 4];
    ushort o[8];
    o[0] = (ushort)f2bf(a.x); o[1] = (ushort)f2bf(a.y);
    o[2] = (ushort)f2bf(a.z); o[3] = (ushort)f2bf(a.w);
    o[4] = (ushort)f2bf(b.x); o[5] = (ushort)f2bf(b.y);
    o[6] = (ushort)f2bf(b.z); o[7] = (ushort)f2bf(b.w);
    *(uint4*)&out[idx] = *(uint4*)o;
}

// ---------------- weight prep ----------------
// sage: aw[h][k]: k<128: ws[k][h]; k<256: wn[k-128][h]; k==256: bias[h]; else 0
__global__ void prep_sage_w(const float* __restrict__ wsx, const float* __restrict__ wnx,
                            const float* __restrict__ b, ushort* __restrict__ aw) {
    int idx = blockIdx.x * 256 + threadIdx.x;
    if (idx >= 128 * KW) return;
    int h = idx / KW;
    int k = idx - h * KW;
    float v = 0.f;
    if (k < 128) v = wsx[(size_t)k * 128 + h];
    else if (k < 256) v = wnx[(size_t)(k - 128) * 128 + h];
    else if (k == 256) v = b[h];
    aw[idx] = (ushort)f2bf(v);
}

// zs weights: aw[h][k]: k<128: mw1[k][h]; k==128: mb1[h]; else 0
__global__ void prep_zs_w(const float* __restrict__ mw1, const float* __restrict__ mb1,
                          ushort* __restrict__ aw) {
    int idx = blockIdx.x * 256 + threadIdx.x;
    if (idx >= 128 * KS) return;
    int h = idx / KS;
    int k = idx - h * KS;
    float v = 0.f;
    if (k < 128) v = mw1[(size_t)k * 128 + h];
    else if (k == 128) v = mb1[h];
    aw[idx] = (ushort)f2bf(v);
}

// zd weights: aw[h][k] = mw1[128+k][h], k<128
__global__ void prep_zd_w(const float* __restrict__ mw1, ushort* __restrict__ aw) {
    int idx = blockIdx.x * 256 + threadIdx.x;
    if (idx >= 128 * KD) return;
    int h = idx / KD;
    int k = idx - h * KD;
    aw[idx] = (ushort)f2bf(mw1[(size_t)(128 + k) * 128 + h]);
}

// ---------------- mean aggregation (bf16, fp32 accum, 4x unrolled) ----------

__global__ __launch_bounds__(256) void agg_mean_bf16(
    const ushort* __restrict__ h, const int* __restrict__ csr_src,
    const int* __restrict__ row_ptr, const float* __restrict__ inv_deg,
    ushort* __restrict__ mean) {
    int node = blockIdx.x * 4 + (threadIdx.x >> 6);
    int lane = threadIdx.x & 63;
    int s = row_ptr[node], e = row_ptr[node + 1];
    float a0 = 0.f, a1 = 0.f;
    int i = s;
    for (; i + 4 <= e; i += 4) {
        int n0 = csr_src[i], n1 = csr_src[i + 1], n2 = csr_src[i + 2], n3 = csr_src[i + 3];
        unsigned u0 = *(const unsigned*)(h + (size_t)n0 * F + lane * 2);
        unsigned u1 = *(const unsigned*)(h + (size_t)n1 * F + lane * 2);
        unsigned u2 = *(const unsigned*)(h + (size_t)n2 * F + lane * 2);
        unsigned u3 = *(const unsigned*)(h + (size_t)n3 * F + lane * 2);
        a0 += bflo(u0) + bflo(u1) + bflo(u2) + bflo(u3);
        a1 += bfhi(u0) + bfhi(u1) + bfhi(u2) + bfhi(u3);
    }
    for (; i < e; ++i) {
        int nid = csr_src[i];
        unsigned u = *(const unsigned*)(h + (size_t)nid * F + lane * 2);
        a0 += bflo(u);
        a1 += bfhi(u);
    }
    float iv = inv_deg[node];
    ushort o[2] = {(ushort)f2bf(a0 * iv), (ushort)f2bf(a1 * iv)};
    *(unsigned*)(mean + (size_t)node * F + lane * 2) = *(unsigned*)o;
}

// ---------------- SAGE layer via MFMA (weight-stationary) ----------------
#define STILE 8
__global__ __launch_bounds__(256) void sage_gemm_mfma(
    const ushort* __restrict__ hb, const ushort* __restrict__ mb,
    const ushort* __restrict__ aw, ushort* __restrict__ hout) {
    int t = threadIdx.x;
    int lane = t & 63, w = t >> 6;
    int l31 = lane & 31, hf = lane >> 5;

    bf16x8 afrag[17];
    const ushort* ap = aw + (size_t)(w * 32 + l31) * KW + hf * 8;
#pragma unroll
    for (int f = 0; f < 17; ++f) afrag[f] = *(const bf16x8*)(ap + f * 16);

    int tile0 = blockIdx.x * STILE;
    for (int tt = 0; tt < STILE; ++tt) {
        int tile = tile0 + tt;
        if (tile >= N_NODES / 32) break;
        int n = tile * 32 + l31;
        const ushort* bs = hb + (size_t)n * F + hf * 8;
        const ushort* bd = mb + (size_t)n * F + hf * 8;

        f32x16 acc1, acc2;
#pragma unroll
        for (int r = 0; r < 16; ++r) { acc1[r] = 0.f; acc2[r] = 0.f; }
#pragma unroll
        for (int f = 0; f < 8; ++f) {
            bf16x8 b = *(const bf16x8*)(bs + f * 16);
            acc1 = __builtin_amdgcn_mfma_f32_32x32x16_bf16(afrag[f], b, acc1, 0, 0, 0);
        }
#pragma unroll
        for (int f = 0; f < 8; ++f) {
            bf16x8 b = *(const bf16x8*)(bd + f * 16);
            acc2 = __builtin_amdgcn_mfma_f32_32x32x16_bf16(afrag[8 + f], b, acc2, 0, 0, 0);
        }
        bf16x8 bx;
#pragma unroll
        for (int j = 0; j < 8; ++j) bx[j] = 0;
        if (hf == 0) bx[0] = (short)0x3F80;   // k=256: bias row * 1.0
        acc2 = __builtin_amdgcn_mfma_f32_32x32x16_bf16(afrag[16], bx, acc2, 0, 0, 0);

#pragma unroll
        for (int g = 0; g < 4; ++g) {
            ushort o4[4];
#pragma unroll
            for (int j = 0; j < 4; ++j) {
                float v = acc1[g * 4 + j] + acc2[g * 4 + j];
                v = v > 0.f ? v : 0.01f * v;
                o4[j] = (ushort)f2bf(v);
            }
            *(uint2*)(hout + (size_t)n * F + w * 32 + g * 8 + hf * 4) = *(uint2*)o4;
        }
    }
}

// ---------------- zs/zd precompute via MFMA ----------------
// zs[n][h] = sum_k h3[n][k]*mw1[k][h] + mb1[h] ; zd[n][h] = sum_k h3[n][k]*mw1[128+k][h]
__global__ __launch_bounds__(256) void mlp_z_mfma(
    const ushort* __restrict__ hb, const ushort* __restrict__ aws,
    const ushort* __restrict__ awd, _Float16* __restrict__ zs,
    _Float16* __restrict__ zd) {
    int t = threadIdx.x;
    int lane = t & 63, w = t >> 6;
    int l31 = lane & 31, hf = lane >> 5;

    bf16x8 afs[9], afd[8];
    const ushort* aps = aws + (size_t)(w * 32 + l31) * KS + hf * 8;
    const ushort* apd = awd + (size_t)(w * 32 + l31) * KD + hf * 8;
#pragma unroll
    for (int f = 0; f < 9; ++f) afs[f] = *(const bf16x8*)(aps + f * 16);
#pragma unroll
    for (int f = 0; f < 8; ++f) afd[f] = *(const bf16x8*)(apd + f * 16);

    int tile0 = blockIdx.x * STILE;
    for (int tt = 0; tt < STILE; ++tt) {
        int tile = tile0 + tt;
        if (tile >= N_NODES / 32) break;
        int n = tile * 32 + l31;
        const ushort* bp = hb + (size_t)n * F + hf * 8;

        f32x16 accS, accD;
#pragma unroll
        for (int r = 0; r < 16; ++r) { accS[r] = 0.f; accD[r] = 0.f; }
#pragma unroll
        for (int f = 0; f < 8; ++f) {
            bf16x8 b = *(const bf16x8*)(bp + f * 16);
            accS = __builtin_amdgcn_mfma_f32_32x32x16_bf16(afs[f], b, accS, 0, 0, 0);
            accD = __builtin_amdgcn_mfma_f32_32x32x16_bf16(afd[f], b, accD, 0, 0, 0);
        }
        bf16x8 bx;
#pragma unroll
        for (int j = 0; j < 8; ++j) bx[j] = 0;
        if (hf == 0) bx[0] = (short)0x3F80;   // k=128: bias row * 1.0
        accS = __builtin_amdgcn_mfma_f32_32x32x16_bf16(afs[8], bx, accS, 0, 0, 0);

#pragma unroll
        for (int g = 0; g < 4; ++g) {
            half4 os, od;
#pragma unroll
            for (int j = 0; j < 4; ++j) {
                os[j] = (_Float16)accS[g * 4 + j];
                od[j] = (_Float16)accD[g * 4 + j];
            }
            int col = w * 32 + g * 8 + hf * 4;
            *(half4*)(zs + (size_t)n * F + col) = os;
            *(half4*)(zd + (size_t)n * F + col) = od;
        }
    }
}

// ---------------- final edge kernel: gather + relu + 128->2 dot -------------
// 16 lanes per edge; lane fl owns feats fl*8..fl*8+7
__global__ __launch_bounds__(256) void edge_final(
    const _Float16* __restrict__ zs, const _Float16* __restrict__ zd,
    const float* __restrict__ ef,
    const int* __restrict__ src, const int* __restrict__ dst,
    const float* __restrict__ mw1, const float* __restrict__ mw2,
    const float* __restrict__ mb2, float* __restrict__ out) {
    int t = threadIdx.x;
    int g = t >> 4;       // edge slot 0..15
    int fl = t & 15;      // feature chunk

    float wf[8], w2a[8], w2b[8];
#pragma unroll
    for (int j = 0; j < 8; ++j) {
        int feat = fl * 8 + j;
        wf[j]  = mw1[(size_t)256 * 128 + feat];
        float2 v = *(const float2*)&mw2[feat * 2];
        w2a[j] = v.x; w2b[j] = v.y;
    }
    float b20 = mb2[0], b21 = mb2[1];

    int e0 = blockIdx.x * (16 * EROUNDS);
#pragma unroll 2
    for (int r = 0; r < EROUNDS; ++r) {
        int e = e0 + r * 16 + g;
        int is = src[e], id = dst[e];
        float efv = ef[e];
        half8 a = *(const half8*)(zs + (size_t)is * F + fl * 8);
        half8 b = *(const half8*)(zd + (size_t)id * F + fl * 8);
        float p0 = 0.f, p1 = 0.f;
#pragma unroll
        for (int j = 0; j < 8; ++j) {
            float v = (float)a[j] + (float)b[j] + efv * wf[j];
            float hh = fmaxf(v, 0.f);
            p0 += hh * w2a[j];
            p1 += hh * w2b[j];
        }
#pragma unroll
        for (int m = 1; m < 16; m <<= 1) {
            p0 += __shfl_xor(p0, m, 64);
            p1 += __shfl_xor(p1, m, 64);
        }
        if (fl == 0) *(float2*)&out[(size_t)e * 2] = make_float2(p0 + b20, p1 + b21);
    }
}

// ---------------- launch ----------------

extern "C" void kernel_launch(void* const* d_in, const int* in_sizes, int n_in,
                              void* d_out, int out_size, void* d_ws, size_t ws_size,
                              hipStream_t stream) {
    const float* node_feats = (const float*)d_in[0];
    const float* edge_feats = (const float*)d_in[1];
    const int*   src = (const int*)d_in[2];
    const int*   dst = (const int*)d_in[3];
    const float* ws0 = (const float*)d_in[4];
    const float* wn0 = (const float*)d_in[5];
    const float* b0  = (const float*)d_in[6];
    const float* ws1 = (const float*)d_in[7];
    const float* wn1 = (const float*)d_in[8];
    const float* b1  = (const float*)d_in[9];
    const float* ws2 = (const float*)d_in[10];
    const float* wn2 = (const float*)d_in[11];
    const float* b2  = (const float*)d_in[12];
    const float* mw1 = (const float*)d_in[13];
    const float* mb1 = (const float*)d_in[14];
    const float* mw2 = (const float*)d_in[15];
    const float* mb2 = (const float*)d_in[16];
    float* out = (float*)d_out;

    char* ws = (char*)d_ws;
    size_t off = 0;
    auto alloc = [&](size_t bytes) {
        size_t o = off;
        off += (bytes + 511) & ~(size_t)511;
        return o;
    };
    ushort* nfb  = (ushort*)(ws + alloc((size_t)N_NODES * F * 2));
    ushort* hb0  = (ushort*)(ws + alloc((size_t)N_NODES * F * 2));
    ushort* hb1  = (ushort*)(ws + alloc((size_t)N_NODES * F * 2));
    ushort* meanb= (ushort*)(ws + alloc((size_t)N_NODES * F * 2));
    int*   deg  = (int*)  (ws + alloc((size_t)N_NODES * 4));
    float* invd = (float*)(ws + alloc((size_t)N_NODES * 4));
    int*   rowp = (int*)  (ws + alloc(((size_t)N_NODES + 1) * 4));
    int*   cur  = (int*)  (ws + alloc((size_t)N_NODES * 4));
    int*   csrc = (int*)  (ws + alloc((size_t)N_EDGES * 4));
    ushort* aw0 = (ushort*)(ws + alloc((size_t)128 * KW * 2));
    ushort* aw1 = (ushort*)(ws + alloc((size_t)128 * KW * 2));
    ushort* aw2 = (ushort*)(ws + alloc((size_t)128 * KW * 2));
    ushort* awS = (ushort*)(ws + alloc((size_t)128 * KS * 2));
    ushort* awD = (ushort*)(ws + alloc((size_t)128 * KD * 2));
    // aliases: meanb dead after layer-2 gemm; nfb dead after layer-0 gemm
    _Float16* zs = (_Float16*)meanb;
    _Float16* zd = (_Float16*)nfb;

    hipMemsetAsync(deg, 0, (size_t)N_NODES * 4, stream);
    count_deg_kernel<<<(N_EDGES + 255) / 256, 256, 0, stream>>>(dst, deg, N_EDGES);
    scan_kernel<<<1, 1024, 0, stream>>>(deg, rowp, cur, invd);
    fill_csr_kernel<<<(N_EDGES + 255) / 256, 256, 0, stream>>>(src, dst, cur, csrc, N_EDGES);

    prep_sage_w<<<(128 * KW + 255) / 256, 256, 0, stream>>>(ws0, wn0, b0, aw0);
    prep_sage_w<<<(128 * KW + 255) / 256, 256, 0, stream>>>(ws1, wn1, b1, aw1);
    prep_sage_w<<<(128 * KW + 255) / 256, 256, 0, stream>>>(ws2, wn2, b2, aw2);
    prep_zs_w<<<(128 * KS + 255) / 256, 256, 0, stream>>>(mw1, mb1, awS);
    prep_zd_w<<<(128 * KD + 255) / 256, 256, 0, stream>>>(mw1, awD);
    convert_bf16_kernel<<<(N_NODES * F / 8 + 255) / 256, 256, 0, stream>>>(node_feats, nfb);

    int ggrid = (N_NODES / 32 + STILE - 1) / STILE;
    const ushort* hin = nfb;
    ushort* houts[3] = {hb0, hb1, hb0};
    const ushort* aws_[3] = {aw0, aw1, aw2};
    for (int l = 0; l < 3; ++l) {
        agg_mean_bf16<<<N_NODES / 4, 256, 0, stream>>>(hin, csrc, rowp, invd, meanb);
        sage_gemm_mfma<<<ggrid, 256, 0, stream>>>(hin, meanb, aws_[l], houts[l]);
        hin = houts[l];
    }
    mlp_z_mfma<<<ggrid, 256, 0, stream>>>(hb0, awS, awD, zs, zd);
    edge_final<<<N_EDGES / (16 * EROUNDS), 256, 0, stream>>>(
        zs, zd, edge_feats, src, dst, mw1, mw2, mb2, out);
}